// Round 1
// baseline (80.696 us; speedup 1.0000x reference)
//
#include <hip/hip_runtime.h>
#include <math.h>

// Problem constants (from reference): N=8192, C=19, M=10, K=64
#define NN   8192
#define KK   64
#define CMV  190      // C*M
#define TN   16       // n-rows per block
#define NTHREADS 192  // 3 waves; thread t owns cm=t (t<190)

// Pairwise fraction combine: num/den pair tree.
// a/u + b/v = (a*v + b*u) / (u*v)
#define COMB(i, s)                                        \
  do {                                                    \
    num[i] = num[i] * den[(i)+(s)] + num[(i)+(s)] * den[i]; \
    den[i] = den[i] * den[(i)+(s)];                       \
  } while (0)

__global__ __launch_bounds__(NTHREADS)
void mls_sim_kernel(const float* __restrict__ x,
                    const float* __restrict__ xvar,
                    const float* __restrict__ proto,
                    const float* __restrict__ pvar,
                    float* __restrict__ out)
{
  __shared__ float xs[TN * KK];
  __shared__ float xvs[TN * KK];

  const int tid = threadIdx.x;
  const int n0  = blockIdx.x * TN;

  // Stage x / x_var tile: rows n0..n0+TN-1 are contiguous in memory.
  {
    const float4* gx  = (const float4*)(x    + (size_t)n0 * KK);
    const float4* gxv = (const float4*)(xvar + (size_t)n0 * KK);
    float4* sx  = (float4*)xs;
    float4* sxv = (float4*)xvs;
    for (int i = tid; i < TN * KK / 4; i += NTHREADS) {
      sx[i]  = gx[i];
      sxv[i] = gxv[i];
    }
  }
  __syncthreads();

  const int cm = tid;
  if (cm >= CMV) return;  // no barriers after this point

  float acc_frac[TN];
  float acc_log2[TN];
#pragma unroll
  for (int n = 0; n < TN; ++n) { acc_frac[n] = 0.f; acc_log2[n] = 0.f; }

#pragma unroll
  for (int kc = 0; kc < 4; ++kc) {
    const int kb = kc * 16;

    // Per-thread prototype chunk (16 mean + 16 var) in registers.
    float pc[16], pvc[16];
    {
      const float4* pp  = (const float4*)(proto + (size_t)cm * KK + kb);
      const float4* ppv = (const float4*)(pvar  + (size_t)cm * KK + kb);
#pragma unroll
      for (int q = 0; q < 4; ++q) {
        float4 t = pp[q];
        pc[4*q+0] = t.x; pc[4*q+1] = t.y; pc[4*q+2] = t.z; pc[4*q+3] = t.w;
        float4 u = ppv[q];
        pvc[4*q+0] = u.x; pvc[4*q+1] = u.y; pvc[4*q+2] = u.z; pvc[4*q+3] = u.w;
      }
    }

#pragma unroll
    for (int n = 0; n < TN; ++n) {
      // Broadcast LDS reads of this row's x chunk (same addr across lanes).
      float xk[16], xvk[16];
      {
        const float4* sx4  = (const float4*)(xs  + n * KK + kb);
        const float4* sxv4 = (const float4*)(xvs + n * KK + kb);
#pragma unroll
        for (int q = 0; q < 4; ++q) {
          float4 t = sx4[q];
          xk[4*q+0] = t.x; xk[4*q+1] = t.y; xk[4*q+2] = t.z; xk[4*q+3] = t.w;
          float4 u = sxv4[q];
          xvk[4*q+0] = u.x; xvk[4*q+1] = u.y; xvk[4*q+2] = u.z; xvk[4*q+3] = u.w;
        }
      }

      float num[16], den[16];
#pragma unroll
      for (int i = 0; i < 16; ++i) {
        float d = pc[i] - xk[i];
        num[i] = d * d;
        den[i] = pvc[i] + xvk[i];
      }
      // Binary combine tree: 15 combines -> single num/den for the chunk.
      COMB(0,1);  COMB(2,1);  COMB(4,1);  COMB(6,1);
      COMB(8,1);  COMB(10,1); COMB(12,1); COMB(14,1);
      COMB(0,2);  COMB(4,2);  COMB(8,2);  COMB(12,2);
      COMB(0,4);  COMB(8,4);
      COMB(0,8);

      acc_frac[n] += num[0] * __builtin_amdgcn_rcpf(den[0]);
      acc_log2[n] += __builtin_amdgcn_logf(den[0]);  // log2(x)
    }
  }

  const float c1  = -0.5f / (float)KK;
  const float ln2 = 0.69314718055994530942f;
#pragma unroll
  for (int n = 0; n < TN; ++n) {
    out[(size_t)(n0 + n) * CMV + cm] = c1 * (acc_frac[n] + ln2 * acc_log2[n]);
  }
}

extern "C" void kernel_launch(void* const* d_in, const int* in_sizes, int n_in,
                              void* d_out, int out_size, void* d_ws, size_t ws_size,
                              hipStream_t stream) {
  const float* x     = (const float*)d_in[0];
  const float* xvar  = (const float*)d_in[1];
  const float* proto = (const float*)d_in[2];
  const float* pvar  = (const float*)d_in[3];
  float* out = (float*)d_out;

  dim3 grid(NN / TN);       // 512 blocks
  dim3 block(NTHREADS);     // 192 threads
  mls_sim_kernel<<<grid, block, 0, stream>>>(x, xvar, proto, pvar, out);
}